// Round 3
// baseline (463.362 us; speedup 1.0000x reference)
//
#include <hip/hip_runtime.h>
#include <hip/hip_bf16.h>
#include <cstdint>

#define N_TOK 16384
#define HID   4096
#define NEXP  64
#define AUXW  0.01f

typedef const __attribute__((address_space(1))) void gvoid_t;
typedef __attribute__((address_space(3))) void lvoid_t;

__device__ __forceinline__ void async_cp16(const void* gsrc, void* ldst) {
  __builtin_amdgcn_global_load_lds((gvoid_t*)gsrc, (lvoid_t*)ldst, 16, 0, 0);
}

// 256 blocks x 512 threads. Block computes logits for 64 tokens x 64 experts,
// then does softmax-free top-2 + outputs.
// LDS (64KB): double-buffered {hs[64][64] , W[64][64]} fp32 tiles, XOR-granule
// swizzled so both staging (linear, global_load_lds) and b128 fragment reads
// are bank-conflict-free. Epilogue regions reuse the staging LDS.
__global__ __launch_bounds__(512, 2) void router_main(
    const float* __restrict__ hs, const float* __restrict__ Wg,
    float* __restrict__ out, float* __restrict__ Sacc) {
  __shared__ char smem[65536];
  float* lds = (float*)smem;

  const int tid  = threadIdx.x;
  const int kg   = tid >> 8;     // K-split group 0/1
  const int t256 = tid & 255;
  const int tx   = t256 & 15;    // expert-group
  const int ty   = t256 >> 4;    // token-group
  const int tb   = blockIdx.x << 6;  // first token of tile

  float acc[4][4];
#pragma unroll
  for (int i = 0; i < 4; ++i)
#pragma unroll
    for (int j = 0; j < 4; ++j) acc[i][j] = 0.f;

  // ---- stage one KC=64 chunk into buffer `buf` (async, width-16) ----
  auto stage = [&](int buf, int chunk) {
    const int k0 = chunk << 6;          // float col base
    float* dst = lds + buf * 8192;      // 8192 floats per buffer pair
    // hs tile: 1024 granules of 16B; thread handles G = tid, tid+512
#pragma unroll
    for (int it = 0; it < 2; ++it) {
      int G = tid + (it << 9);
      int row = G >> 4, g = G & 15;
      int gs = g ^ (row & 15);          // pre-swizzled global source
      async_cp16(hs + (size_t)(tb + row) * HID + k0 + (gs << 2), dst + (G << 2));
    }
#pragma unroll
    for (int it = 0; it < 2; ++it) {
      int G = tid + (it << 9);
      int row = G >> 4, g = G & 15;     // row = expert
      int gs = g ^ (row & 15);
      async_cp16(Wg + (size_t)row * HID + k0 + (gs << 2), dst + 4096 + (G << 2));
    }
  };

  // ---- compute on buffer `buf`: this kg covers 32 of the 64 k's ----
  auto compute = [&](int buf) {
    const float* hsb = lds + buf * 8192;
    const float* Wb  = hsb + 4096;
    const int kb = kg << 5;
#pragma unroll
    for (int kk = 0; kk < 32; kk += 4) {
      const int kq = (kb + kk) >> 2;    // granule col 0..15
      float4 a[4], b[4];
#pragma unroll
      for (int i = 0; i < 4; ++i) {
        int row = ty + (i << 4);        // row&15 == ty
        a[i] = *(const float4*)(hsb + (row << 6) + ((kq ^ ty) << 2));
      }
#pragma unroll
      for (int j = 0; j < 4; ++j) {
        int row = tx + (j << 4);        // row&15 == tx
        b[j] = *(const float4*)(Wb + (row << 6) + ((kq ^ tx) << 2));
      }
#pragma unroll
      for (int i = 0; i < 4; ++i)
#pragma unroll
        for (int j = 0; j < 4; ++j) {
          acc[i][j] = fmaf(a[i].x, b[j].x, acc[i][j]);
          acc[i][j] = fmaf(a[i].y, b[j].y, acc[i][j]);
          acc[i][j] = fmaf(a[i].z, b[j].z, acc[i][j]);
          acc[i][j] = fmaf(a[i].w, b[j].w, acc[i][j]);
        }
    }
  };

  // ---- double-buffered main loop over 64 K-chunks ----
  stage(0, 0);
  __syncthreads();
  for (int c = 0; c < 63; ++c) {
    stage((c + 1) & 1, c + 1);   // async prefetch next
    compute(c & 1);
    __syncthreads();             // drains vmcnt(0): next buffer ready
  }
  compute(1);
  __syncthreads();

  // ---- epilogue: reduce K-split, per-token top-2, outputs ----
  float* red   = lds;                      // [256][16] partial logits (16KB)
  float* lg    = lds + 4096;               // logits [64][73] padded
  float* S_lds = lds + 4096 + 64 * 73;     // per-expert weight sums
  int*   e1a   = (int*)(S_lds + 64);
  int*   e2a   = e1a + 64;

  if (kg == 1) {
#pragma unroll
    for (int i = 0; i < 4; ++i)
#pragma unroll
      for (int j = 0; j < 4; ++j) red[t256 * 16 + i * 4 + j] = acc[i][j];
  }
  if (tid < 64) S_lds[tid] = 0.f;
  __syncthreads();

  if (kg == 0) {
#pragma unroll
    for (int i = 0; i < 4; ++i)
#pragma unroll
      for (int j = 0; j < 4; ++j) {
        float v = acc[i][j] + red[t256 * 16 + i * 4 + j];
        lg[(ty + (i << 4)) * 73 + tx + (j << 4)] = v;
      }
  }
  __syncthreads();

  if (tid < 64) {
    const float* row = lg + tid * 73;
    float m1 = -1e30f, m2 = -1e30f;
    int   i1 = 0,      i2 = 0;
    for (int e = 0; e < NEXP; ++e) {
      float v = row[e];
      if (v > m1)      { m2 = m1; i2 = i1; m1 = v; i1 = e; }
      else if (v > m2) { m2 = v;  i2 = e; }
    }
    // renormalized top-2 weights: softmax over {m1,m2} (full Z cancels)
    float q  = expf(m2 - m1);
    float w1 = 1.f / (1.f + q);
    float w2 = q * w1;
    float* comb = out + (size_t)N_TOK * 2 * NEXP;
    comb[(size_t)(tb + tid) * 2]     = w1;
    comb[(size_t)(tb + tid) * 2 + 1] = w2;
    e1a[tid] = i1;
    e2a[tid] = i2;
    atomicAdd(&S_lds[i1], w1);
    atomicAdd(&S_lds[i2], w2);
  }
  __syncthreads();

  if (tid < 64) atomicAdd(&Sacc[tid], S_lds[tid]);

  // cooperative one-hot dispatch-mask write: 64 tok x 2 slots x 64 experts
#pragma unroll
  for (int it = 0; it < 4; ++it) {
    int f   = it * 512 + tid;     // [0,2048) float4 granules
    int tok = f >> 5;
    int rem = f & 31;
    int sl  = rem >> 4;
    int g   = rem & 15;
    int sel = sl ? e2a[tok] : e1a[tok];
    float4 v; v.x = v.y = v.z = v.w = 0.f;
    int base = g << 2;
    if (sel >= base && sel < base + 4) ((float*)&v)[sel - base] = 1.0f;
    *(float4*)(out + ((size_t)(tb + tok) * 2 + sl) * 64 + base) = v;
  }
}

__global__ void aux_k(const float* __restrict__ S, float* __restrict__ out) {
  float v = S[threadIdx.x];
  float s = v * v;
#pragma unroll
  for (int off = 32; off > 0; off >>= 1) s += __shfl_down(s, off);
  if (threadIdx.x == 0)
    out[(size_t)N_TOK * 2 * NEXP + (size_t)N_TOK * 2] = s * (AUXW / (float)N_TOK);
}

extern "C" void kernel_launch(void* const* d_in, const int* in_sizes, int n_in,
                              void* d_out, int out_size, void* d_ws, size_t ws_size,
                              hipStream_t stream) {
  const float* hs = (const float*)d_in[0];
  const float* Wg = (const float*)d_in[1];
  float* out = (float*)d_out;
  float* S   = (float*)d_ws;
  hipMemsetAsync(d_ws, 0, NEXP * sizeof(float), stream);
  hipLaunchKernelGGL(router_main, dim3(N_TOK / 64), dim3(512), 0, stream,
                     hs, Wg, out, S);
  hipLaunchKernelGGL(aux_k, dim3(1), dim3(64), 0, stream, S, out);
}

// Round 4
// 425.082 us; speedup vs baseline: 1.0901x; 1.0901x over previous
//
#include <hip/hip_runtime.h>
#include <hip/hip_bf16.h>
#include <cstdint>

#define N_TOK 16384
#define HID   4096
#define NEXP  64
#define AUXW  0.01f
#define TOKB  32
#define KC    32
#define NCH   (HID/KC)   // 128

typedef __attribute__((ext_vector_type(4))) _Float16 f16x4;
typedef __attribute__((ext_vector_type(8))) _Float16 f16x8;
typedef __attribute__((ext_vector_type(4))) float f32x4;

// byte offsets within one LDS buffer (A tiles: [32][32] f16; W tiles: [64][32] f16)
#define AH 0
#define AM 2048
#define AL 4096
#define WH 6144
#define WM 10240
#define WL 14336
#define BUFSZ 18432

// 3-way fp16 split of 4 fp32 values: x = H + M + L with residual ~2^-33 |x|.
__device__ __forceinline__ void split3(float4 p, f16x4& H, f16x4& M, f16x4& L) {
  float f[4] = {p.x, p.y, p.z, p.w};
  f16x4 h, m, l;
#pragma unroll
  for (int j = 0; j < 4; ++j) {
    _Float16 hh = (_Float16)f[j];
    float r1 = f[j] - (float)hh;
    _Float16 mm = (_Float16)r1;
    float r2 = r1 - (float)mm;
    h[j] = hh; m[j] = mm; l[j] = (_Float16)r2;
  }
  H = h; M = m; L = l;
}

// 512 blocks x 256 threads; block = 32 tokens x 64 experts, K staged in 32-chunks.
// Logits via 6-term split-fp16 MFMA (fp32-grade accuracy), then top-2 epilogue.
__global__ __launch_bounds__(256, 2) void router_main(
    const float* __restrict__ hs, const float* __restrict__ Wg,
    float* __restrict__ out, float* __restrict__ Sacc) {
  __shared__ __align__(16) char smem[2 * BUFSZ];

  const int tid  = threadIdx.x;
  const int tb   = blockIdx.x * TOKB;
  const int lane = tid & 63;
  const int wv   = tid >> 6;          // wave 0..3
  const int l15  = lane & 15;
  const int l4   = lane >> 4;
  const int rbase = (wv >> 1) * 16;   // token-tile base (0/16)
  const int cbase = (wv & 1) * 32;    // expert-tile base (0/32)

  // staging thread mapping: 1 hs float4 + 2 W float4 per thread per chunk
  const int sa_row = tid >> 3, sa_fq = tid & 7;     // hs rows 0..31, 8 float4/row
  const int q1 = tid + 256;
  const int sw_row1 = q1 >> 3, sw_fq1 = q1 & 7;     // W rows 32..63

  f32x4 acc0 = {0.f, 0.f, 0.f, 0.f}, acc1 = {0.f, 0.f, 0.f, 0.f};

  char* b0 = smem;
  char* b1 = smem + BUFSZ;

  // fragment LDS offsets (chunk-invariant). Granule(16B) XOR-swizzle vs row.
  const int a_r = rbase + l15;
  const int aoff = a_r * 64 + ((l4 ^ (a_r & 3)) << 4);
  const int e0r = cbase + l15;
  const int e1r = cbase + 16 + l15;
  const int boff0 = e0r * 64 + ((l4 ^ (e0r & 3)) << 4);
  const int boff1 = e1r * 64 + ((l4 ^ (e1r & 3)) << 4);

  auto compute = [&](const char* buf) {
    f16x8 ah = *(const f16x8*)(buf + AH + aoff);
    f16x8 am = *(const f16x8*)(buf + AM + aoff);
    f16x8 al = *(const f16x8*)(buf + AL + aoff);
    f16x8 bh0 = *(const f16x8*)(buf + WH + boff0);
    f16x8 bm0 = *(const f16x8*)(buf + WM + boff0);
    f16x8 bl0 = *(const f16x8*)(buf + WL + boff0);
    f16x8 bh1 = *(const f16x8*)(buf + WH + boff1);
    f16x8 bm1 = *(const f16x8*)(buf + WM + boff1);
    f16x8 bl1 = *(const f16x8*)(buf + WL + boff1);
    acc0 = __builtin_amdgcn_mfma_f32_16x16x32_f16(ah, bh0, acc0, 0, 0, 0);
    acc1 = __builtin_amdgcn_mfma_f32_16x16x32_f16(ah, bh1, acc1, 0, 0, 0);
    acc0 = __builtin_amdgcn_mfma_f32_16x16x32_f16(ah, bm0, acc0, 0, 0, 0);
    acc1 = __builtin_amdgcn_mfma_f32_16x16x32_f16(ah, bm1, acc1, 0, 0, 0);
    acc0 = __builtin_amdgcn_mfma_f32_16x16x32_f16(am, bh0, acc0, 0, 0, 0);
    acc1 = __builtin_amdgcn_mfma_f32_16x16x32_f16(am, bh1, acc1, 0, 0, 0);
    acc0 = __builtin_amdgcn_mfma_f32_16x16x32_f16(ah, bl0, acc0, 0, 0, 0);
    acc1 = __builtin_amdgcn_mfma_f32_16x16x32_f16(ah, bl1, acc1, 0, 0, 0);
    acc0 = __builtin_amdgcn_mfma_f32_16x16x32_f16(al, bh0, acc0, 0, 0, 0);
    acc1 = __builtin_amdgcn_mfma_f32_16x16x32_f16(al, bh1, acc1, 0, 0, 0);
    acc0 = __builtin_amdgcn_mfma_f32_16x16x32_f16(am, bm0, acc0, 0, 0, 0);
    acc1 = __builtin_amdgcn_mfma_f32_16x16x32_f16(am, bm1, acc1, 0, 0, 0);
  };

  auto stage_write = [&](char* buf, float4 A0, float4 W0, float4 W1) {
    f16x4 H, M, L;
    split3(A0, H, M, L);
    int off = sa_row * 64 + (((sa_fq >> 1) ^ (sa_row & 3)) << 4) + (sa_fq & 1) * 8;
    *(f16x4*)(buf + AH + off) = H;
    *(f16x4*)(buf + AM + off) = M;
    *(f16x4*)(buf + AL + off) = L;
    split3(W0, H, M, L);
    off = sa_row * 64 + (((sa_fq >> 1) ^ (sa_row & 3)) << 4) + (sa_fq & 1) * 8;
    *(f16x4*)(buf + WH + off) = H;
    *(f16x4*)(buf + WM + off) = M;
    *(f16x4*)(buf + WL + off) = L;
    split3(W1, H, M, L);
    off = sw_row1 * 64 + (((sw_fq1 >> 1) ^ (sw_row1 & 3)) << 4) + (sw_fq1 & 1) * 8;
    *(f16x4*)(buf + WH + off) = H;
    *(f16x4*)(buf + WM + off) = M;
    *(f16x4*)(buf + WL + off) = L;
  };

  auto load3 = [&](int c, float4& A0, float4& W0, float4& W1) {
    A0 = *(const float4*)(hs + (size_t)(tb + sa_row) * HID + c * KC + sa_fq * 4);
    W0 = *(const float4*)(Wg + (size_t)sa_row * HID + c * KC + sa_fq * 4);
    W1 = *(const float4*)(Wg + (size_t)sw_row1 * HID + c * KC + sw_fq1 * 4);
  };

  {
    float4 A0, W0, W1;
    load3(0, A0, W0, W1);
    stage_write(b0, A0, W0, W1);
  }
  __syncthreads();

#pragma unroll 2
  for (int c = 0; c < NCH - 1; ++c) {
    float4 A0, W0, W1;
    load3(c + 1, A0, W0, W1);          // issue early (hidden under compute)
    compute((c & 1) ? b1 : b0);
    stage_write(((c + 1) & 1) ? b1 : b0, A0, W0, W1);  // write late
    __syncthreads();
  }
  compute(b1);   // chunk 127 (odd) lives in b1

  // ---- epilogue: logits -> LDS (reuses buffer 0; final compute read only b1) ----
  float* lg    = (float*)smem;            // [32][73] padded
  float* S_lds = lg + TOKB * 73;          // 64 floats
  int*   e1a   = (int*)(S_lds + 64);      // 32
  int*   e2a   = e1a + 32;                // 32

  {
    const int orow = rbase + l4 * 4;
    const int ocol = cbase + l15;
#pragma unroll
    for (int r = 0; r < 4; ++r) {
      lg[(orow + r) * 73 + ocol]      = acc0[r];
      lg[(orow + r) * 73 + ocol + 16] = acc1[r];
    }
  }
  if (tid < 64) S_lds[tid] = 0.f;
  __syncthreads();

  if (tid < TOKB) {
    const float* row = lg + tid * 73;
    float m1 = -1e30f, m2 = -1e30f;
    int i1 = 0, i2 = 0;
    for (int e = 0; e < NEXP; ++e) {
      float v = row[e];
      if (v > m1)      { m2 = m1; i2 = i1; m1 = v; i1 = e; }
      else if (v > m2) { m2 = v;  i2 = e; }
    }
    // renormalized top-2 = softmax over {m1,m2} (full denominator cancels)
    float qq = expf(m2 - m1);
    float w1 = 1.f / (1.f + qq);
    float w2 = qq * w1;
    float* comb = out + (size_t)N_TOK * 2 * NEXP;
    comb[(size_t)(tb + tid) * 2]     = w1;
    comb[(size_t)(tb + tid) * 2 + 1] = w2;
    e1a[tid] = i1; e2a[tid] = i2;
    atomicAdd(&S_lds[i1], w1);
    atomicAdd(&S_lds[i2], w2);
  }
  __syncthreads();
  if (tid < 64) {
    float s = S_lds[tid];
    if (s != 0.f) atomicAdd(&Sacc[tid], s);
  }

  // cooperative one-hot dispatch-mask write: 32 tok x 2 slots x 64 experts
#pragma unroll
  for (int it = 0; it < 4; ++it) {
    int f = it * 256 + tid;          // 0..1023 float4 granules
    int tok = f >> 5, rem = f & 31, sl = rem >> 4, g = rem & 15;
    int sel = sl ? e2a[tok] : e1a[tok];
    int base = g << 2;
    float4 v;
    v.x = (sel == base)     ? 1.f : 0.f;
    v.y = (sel == base + 1) ? 1.f : 0.f;
    v.z = (sel == base + 2) ? 1.f : 0.f;
    v.w = (sel == base + 3) ? 1.f : 0.f;
    *(float4*)(out + ((size_t)(tb + tok) * 2 + sl) * 64 + base) = v;
  }
}

__global__ void aux_k(const float* __restrict__ S, float* __restrict__ out) {
  float v = S[threadIdx.x];
  float s = v * v;
#pragma unroll
  for (int off = 32; off > 0; off >>= 1) s += __shfl_down(s, off);
  if (threadIdx.x == 0)
    out[(size_t)N_TOK * 2 * NEXP + (size_t)N_TOK * 2] = s * (AUXW / (float)N_TOK);
}

extern "C" void kernel_launch(void* const* d_in, const int* in_sizes, int n_in,
                              void* d_out, int out_size, void* d_ws, size_t ws_size,
                              hipStream_t stream) {
  const float* hs = (const float*)d_in[0];
  const float* Wg = (const float*)d_in[1];
  float* out = (float*)d_out;
  float* S   = (float*)d_ws;
  hipMemsetAsync(d_ws, 0, NEXP * sizeof(float), stream);
  hipLaunchKernelGGL(router_main, dim3(N_TOK / TOKB), dim3(256), 0, stream,
                     hs, Wg, out, S);
  hipLaunchKernelGGL(aux_k, dim3(1), dim3(64), 0, stream, S, out);
}

// Round 5
// 391.235 us; speedup vs baseline: 1.1844x; 1.0865x over previous
//
#include <hip/hip_runtime.h>
#include <cstdint>

#define N_TOK 16384
#define HID   4096
#define NEXP  64
#define AUXW  0.01f
#define TOKB  32
#define KC    64
#define NCH   (HID/KC)        // 64 chunks
#define IMG_CHUNK 24576       // bytes per W-image chunk: 3 levels * 64 rows * 128B

typedef __attribute__((ext_vector_type(4))) _Float16 f16x4;
typedef __attribute__((ext_vector_type(8))) _Float16 f16x8;
typedef __attribute__((ext_vector_type(4))) float f32x4;

typedef const __attribute__((address_space(1))) void gvoid_t;
typedef __attribute__((address_space(3))) void lvoid_t;

__device__ __forceinline__ void async_cp16(const void* g, void* l) {
  __builtin_amdgcn_global_load_lds((gvoid_t*)g, (lvoid_t*)l, 16, 0, 0);
}

// 3-way f16 split: x = H+M+L, dropped residual ~2^-33|x| -> fp32-grade logits
__device__ __forceinline__ void split3_f4(float4 p, f16x4& H, f16x4& M, f16x4& L) {
  float f[4] = {p.x, p.y, p.z, p.w};
#pragma unroll
  for (int j = 0; j < 4; ++j) {
    _Float16 h = (_Float16)f[j];
    float r1 = f[j] - (float)h;
    _Float16 m = (_Float16)r1;
    float r2 = r1 - (float)m;
    H[j] = h; M[j] = m; L[j] = (_Float16)r2;
  }
}

// W (64x4096 f32) -> chunked+swizzled f16 H/M/L image, ready for linear
// global_load_lds staging. image[chunk][level][row][gswz]*16B, gswz=g^(row&7).
__global__ void presplit_w(const float* __restrict__ Wg, char* __restrict__ img) {
  int id = blockIdx.x * 256 + threadIdx.x;   // 0..32767
  int row = id >> 9;                         // 0..63
  int rem = id & 511;
  int chunk = rem >> 3;                      // 0..63
  int g = rem & 7;                           // 0..7 (granule: 8 cols)
  const float* src = Wg + (size_t)row * HID + chunk * KC + g * 8;
  float4 p0 = *(const float4*)src;
  float4 p1 = *(const float4*)(src + 4);
  f16x4 h0, m0, l0, h1, m1, l1;
  split3_f4(p0, h0, m0, l0);
  split3_f4(p1, h1, m1, l1);
  char* base = img + (size_t)chunk * IMG_CHUNK + row * 128 + ((g ^ (row & 7)) << 4);
  *(f16x4*)(base)         = h0;  *(f16x4*)(base + 8)     = h1;
  *(f16x4*)(base + 8192)  = m0;  *(f16x4*)(base + 8200)  = m1;
  *(f16x4*)(base + 16384) = l0;  *(f16x4*)(base + 16392) = l1;
}

// 512 blocks x 256 thr (4 waves = (kg,eg)). Block: 32 tok x 64 exp.
// LDS 60KB: Abuf 12288 (single, 3 lvl x [32][64]f16) + Wbuf 2x24576 (double).
__global__ __launch_bounds__(256, 2) void router_main(
    const float* __restrict__ hs, const char* __restrict__ wimg,
    float* __restrict__ out, float* __restrict__ Sacc) {
  __shared__ __align__(16) char smem[61440];
  char* Abuf = smem;
  char* Wb0 = smem + 12288;
  char* Wb1 = smem + 36864;

  const int tid = threadIdx.x;
  const int tb = blockIdx.x * TOKB;
  const int lane = tid & 63;
  const int wv = tid >> 6;
  const int eg = wv & 1, kg = wv >> 1;
  const int l15 = lane & 15, l4 = lane >> 4;

  // staging mapping: thread covers row=tid>>3 (0..31), granule sg=tid&7 (8 cols)
  const int srow = tid >> 3, sg = tid & 7;
  const float* hsp = hs + (size_t)(tb + srow) * HID + sg * 8;
  const int aslot = srow * 128 + ((sg ^ (srow & 7)) << 4);
  const char* wsrc = wimg + tid * 16;

  // fragment byte offsets within level arrays (A row = token, B row = expert)
  int aoff[2], boff[2];
#pragma unroll
  for (int tg = 0; tg < 2; ++tg) {
    int r = tg * 16 + l15;
    aoff[tg] = r * 128 + (((kg * 4 + l4) ^ (r & 7)) << 4);
  }
#pragma unroll
  for (int bg = 0; bg < 2; ++bg) {
    int r = eg * 32 + bg * 16 + l15;
    boff[bg] = r * 128 + (((kg * 4 + l4) ^ (r & 7)) << 4);
  }

  f32x4 acc[2][2] = {};
  float4 rA0, rA1, rB0, rB1;

  auto loadhs = [&](int c, float4& x0, float4& x1) {
    x0 = *(const float4*)(hsp + (size_t)c * KC);
    x1 = *(const float4*)(hsp + (size_t)c * KC + 4);
  };
  auto stageW = [&](int c, char* dst) {
#pragma unroll
    for (int it = 0; it < 6; ++it)
      async_cp16(wsrc + (size_t)c * IMG_CHUNK + it * 4096, dst + it * 4096 + tid * 16);
  };
  auto writeA = [&](float4 x0, float4 x1) {
    f16x4 h0, m0, l0, h1, m1, l1;
    split3_f4(x0, h0, m0, l0);
    split3_f4(x1, h1, m1, l1);
    f16x8 H, M, L;
#pragma unroll
    for (int j = 0; j < 4; ++j) {
      H[j] = h0[j]; H[j + 4] = h1[j];
      M[j] = m0[j]; M[j + 4] = m1[j];
      L[j] = l0[j]; L[j + 4] = l1[j];
    }
    *(f16x8*)(Abuf + aslot)        = H;
    *(f16x8*)(Abuf + 4096 + aslot) = M;
    *(f16x8*)(Abuf + 8192 + aslot) = L;
  };
  auto compute = [&](const char* W) {
    f16x8 aH[2], aM[2], aL[2], bH[2], bM[2], bL[2];
#pragma unroll
    for (int t = 0; t < 2; ++t) {
      aH[t] = *(const f16x8*)(Abuf + aoff[t]);
      aM[t] = *(const f16x8*)(Abuf + 4096 + aoff[t]);
      aL[t] = *(const f16x8*)(Abuf + 8192 + aoff[t]);
    }
#pragma unroll
    for (int b = 0; b < 2; ++b) {
      bH[b] = *(const f16x8*)(W + boff[b]);
      bM[b] = *(const f16x8*)(W + 8192 + boff[b]);
      bL[b] = *(const f16x8*)(W + 16384 + boff[b]);
    }
#pragma unroll
    for (int t = 0; t < 2; ++t)
#pragma unroll
      for (int b = 0; b < 2; ++b) {
        f32x4 a = acc[t][b];
        a = __builtin_amdgcn_mfma_f32_16x16x32_f16(aH[t], bH[b], a, 0, 0, 0);
        a = __builtin_amdgcn_mfma_f32_16x16x32_f16(aH[t], bM[b], a, 0, 0, 0);
        a = __builtin_amdgcn_mfma_f32_16x16x32_f16(aM[t], bH[b], a, 0, 0, 0);
        a = __builtin_amdgcn_mfma_f32_16x16x32_f16(aH[t], bL[b], a, 0, 0, 0);
        a = __builtin_amdgcn_mfma_f32_16x16x32_f16(aL[t], bH[b], a, 0, 0, 0);
        a = __builtin_amdgcn_mfma_f32_16x16x32_f16(aM[t], bM[b], a, 0, 0, 0);
        acc[t][b] = a;
      }
  };

  // prologue: chunk 0 into Abuf/Wb0; preload hs(1)
  loadhs(0, rA0, rA1);
  stageW(0, Wb0);
  writeA(rA0, rA1);
  loadhs(1, rA0, rA1);
  __syncthreads();

  for (int c = 0; c < NCH - 1; ++c) {
    stageW(c + 1, (c & 1) ? Wb0 : Wb1);       // async -> other W buffer
    int cn = (c + 2 < NCH) ? c + 2 : NCH - 1;
    loadhs(cn, rB0, rB1);                      // depth-2 reg prefetch
    compute((c & 1) ? Wb1 : Wb0);
    // barrier 1: only LDS-reads-done; keeps cp16 + hs loads in flight
    asm volatile("s_waitcnt lgkmcnt(0)\n\ts_barrier" ::: "memory");
    writeA(rA0, rA1);                          // stage hs chunk c+1
    rA0 = rB0; rA1 = rB1;
    __syncthreads();                           // full drain: W + A ready
  }
  compute((NCH - 1) & 1 ? Wb1 : Wb0);          // chunk 63 -> Wb1

  // ---- epilogue (scratch inside Wb0 region; final compute read Abuf+Wb1) ----
  float* red   = (float*)(smem + 12288);       // [32][64] partials from kg=1
  float* lg    = (float*)(smem + 20480);       // [32][73] logits
  float* S_lds = (float*)(smem + 29824);       // 64
  int*   e1a   = (int*)(smem + 30080);         // 32
  int*   e2a   = (int*)(smem + 30208);         // 32

  if (kg == 1) {
#pragma unroll
    for (int t = 0; t < 2; ++t)
#pragma unroll
      for (int b = 0; b < 2; ++b)
#pragma unroll
        for (int r = 0; r < 4; ++r)
          red[(t * 16 + l4 * 4 + r) * 64 + eg * 32 + b * 16 + l15] = acc[t][b][r];
  }
  if (tid < 64) S_lds[tid] = 0.f;
  __syncthreads();
  if (kg == 0) {
#pragma unroll
    for (int t = 0; t < 2; ++t)
#pragma unroll
      for (int b = 0; b < 2; ++b)
#pragma unroll
        for (int r = 0; r < 4; ++r) {
          int tok = t * 16 + l4 * 4 + r, ex = eg * 32 + b * 16 + l15;
          lg[tok * 73 + ex] = acc[t][b][r] + red[tok * 64 + ex];
        }
  }
  __syncthreads();

  if (tid < TOKB) {
    const float* row = lg + tid * 73;
    float m1 = -1e30f, m2 = -1e30f;
    int i1 = 0, i2 = 0;
    for (int e = 0; e < NEXP; ++e) {
      float v = row[e];
      if (v > m1)      { m2 = m1; i2 = i1; m1 = v; i1 = e; }
      else if (v > m2) { m2 = v;  i2 = e; }
    }
    float qq = expf(m2 - m1);           // renorm top-2 = 2-way softmax
    float w1 = 1.f / (1.f + qq);
    float w2 = qq * w1;
    float* comb = out + (size_t)N_TOK * 2 * NEXP;
    comb[(size_t)(tb + tid) * 2]     = w1;
    comb[(size_t)(tb + tid) * 2 + 1] = w2;
    e1a[tid] = i1; e2a[tid] = i2;
    atomicAdd(&S_lds[i1], w1);
    atomicAdd(&S_lds[i2], w2);
  }
  __syncthreads();
  if (tid < 64) {
    float s = S_lds[tid];
    if (s != 0.f) atomicAdd(&Sacc[tid], s);
  }

  // one-hot dispatch mask: 32 tok x 2 slots x 16 float4-granules
#pragma unroll
  for (int it = 0; it < 4; ++it) {
    int f = it * 256 + tid;
    int tok = f >> 5, rem = f & 31, sl = rem >> 4, g = rem & 15;
    int sel = sl ? e2a[tok] : e1a[tok];
    int base = g << 2;
    float4 v;
    v.x = (sel == base)     ? 1.f : 0.f;
    v.y = (sel == base + 1) ? 1.f : 0.f;
    v.z = (sel == base + 2) ? 1.f : 0.f;
    v.w = (sel == base + 3) ? 1.f : 0.f;
    *(float4*)(out + ((size_t)(tb + tok) * 2 + sl) * 64 + base) = v;
  }
}

__global__ void aux_k(const float* __restrict__ S, float* __restrict__ out) {
  float v = S[threadIdx.x];
  float s = v * v;
#pragma unroll
  for (int off = 32; off > 0; off >>= 1) s += __shfl_down(s, off);
  if (threadIdx.x == 0)
    out[(size_t)N_TOK * 2 * NEXP + (size_t)N_TOK * 2] = s * (AUXW / (float)N_TOK);
}

extern "C" void kernel_launch(void* const* d_in, const int* in_sizes, int n_in,
                              void* d_out, int out_size, void* d_ws, size_t ws_size,
                              hipStream_t stream) {
  const float* hs = (const float*)d_in[0];
  const float* Wg = (const float*)d_in[1];
  float* out = (float*)d_out;
  float* S = (float*)d_ws;                     // 64 floats
  char* img = (char*)d_ws + 256;               // 1.5 MB W image
  hipMemsetAsync(d_ws, 0, 256, stream);
  hipLaunchKernelGGL(presplit_w, dim3(128), dim3(256), 0, stream, Wg, img);
  hipLaunchKernelGGL(router_main, dim3(N_TOK / TOKB), dim3(256), 0, stream,
                     hs, img, out, S);
  hipLaunchKernelGGL(aux_k, dim3(1), dim3(64), 0, stream, S, out);
}